// Round 10
// baseline (40.994 us; speedup 1.0000x reference)
//
#include <hip/hip_runtime.h>
#include <math.h>

#define D_IN 768
#define NLAB 28

// ================= bit-location maps per epoch =================
struct Map { int rb[2]; int lb[6]; int wb[4]; };
constexpr Map MP[4] = {
    {{10, 11}, {4, 5, 6, 7, 8, 9}, {0, 1, 2, 3}},
    {{0, 1}, {2, 3, 8, 9, 10, 11}, {4, 5, 6, 7}},
    {{6, 7}, {5, 4, 2, 3, 0, 1}, {8, 9, 10, 11}},
    {{0, 1}, {2, 3, 8, 9, 10, 11}, {4, 5, 6, 7}},
};
constexpr int regPos(int e, int b) { for (int k = 0; k < 2; ++k) if (MP[e].rb[k] == b) return k; return -1; }
constexpr int lanePos(int e, int b) { for (int j = 0; j < 6; ++j) if (MP[e].lb[j] == b) return j; return -1; }
constexpr int wavePos(int e, int b) { for (int m = 0; m < 4; ++m) if (MP[e].wb[m] == b) return m; return -1; }

constexpr int stateOf(int e, int wv, int lane, int r) {
    int i = 0;
    for (int k = 0; k < 2; ++k) i |= ((r >> k) & 1) << MP[e].rb[k];
    for (int j = 0; j < 6; ++j) i |= ((lane >> j) & 1) << MP[e].lb[j];
    for (int m = 0; m < 4; ++m) i |= ((wv >> m) & 1) << MP[e].wb[m];
    return i;
}
constexpr int slotOf(int e, int i) {
    int r = 0, ln = 0, wv = 0;
    for (int k = 0; k < 2; ++k) r |= ((i >> MP[e].rb[k]) & 1) << k;
    for (int j = 0; j < 6; ++j) ln |= ((i >> MP[e].lb[j]) & 1) << j;
    for (int m = 0; m < 4; ++m) wv |= ((i >> MP[e].wb[m]) & 1) << m;
    return (wv << 8) | (ln << 2) | r;
}
constexpr int swzl(int s) { return s ^ (((s >> 4) ^ (s >> 8)) & 15); }  // GF(2)-linear

// ============ cross-lane exchange at distance 2^J — ALL VALU (no LDS pipe) ============
// DPP convention (LLVM AMDGPUAtomicOptimizer): row_shr:N -> lane i reads lane i-N;
// row_shl:N -> lane i reads lane i+N.
template <int J>
__device__ __forceinline__ float lx(float v) {
    if constexpr (J == 0 || J == 1 || J == 3) {
        // xor1: quad_perm[1,0,3,2]=0xB1; xor2: quad_perm[2,3,0,1]=0x4E; xor8: row_ror:8=0x128
        constexpr int ctrl = (J == 0) ? 0xB1 : (J == 1) ? 0x4E : 0x128;
        return __int_as_float(__builtin_amdgcn_update_dpp(
            0, __float_as_int(v), ctrl, 0xF, 0xF, true));
    } else if constexpr (J == 2) {
        // xor4 within 16-row: lanes with bit4=0 need i+4 (row_shl:4), bit4=1 need i-4 (row_shr:4)
        const float tshl = __int_as_float(__builtin_amdgcn_update_dpp(
            0, __float_as_int(v), 0x104, 0xF, 0xF, true));
        const float tshr = __int_as_float(__builtin_amdgcn_update_dpp(
            0, __float_as_int(v), 0x114, 0xF, 0xF, true));
        return (threadIdx.x & 4) ? tshr : tshl;
    } else if constexpr (J == 4) {
#if __has_builtin(__builtin_amdgcn_permlane16_swap)
        auto pr = __builtin_amdgcn_permlane16_swap(__float_as_int(v), __float_as_int(v), false, false);
        // {pr[0], pr[1]} = {v, v[lane^16]} as a set -> partner = sum - v (convention-proof)
        return (__int_as_float((int)pr[0]) + __int_as_float((int)pr[1])) - v;
#else
        return __int_as_float(__builtin_amdgcn_ds_swizzle(__float_as_int(v), 0x401F));
#endif
    } else {
#if __has_builtin(__builtin_amdgcn_permlane32_swap)
        auto pr = __builtin_amdgcn_permlane32_swap(__float_as_int(v), __float_as_int(v), false, false);
        return (__int_as_float((int)pr[0]) + __int_as_float((int)pr[1])) - v;
#else
        return __shfl_xor(v, 32, 64);
#endif
    }
}
__device__ __forceinline__ float waveRed(float v) {
    v += lx<0>(v); v += lx<1>(v); v += lx<2>(v);
    v += lx<3>(v); v += lx<4>(v); v += lx<5>(v);
    return v;
}

// ======= packed-f32 complex helpers: u stored as rr=(ur,ur), im=(-ui,ui) =======
struct CU2 { float2 rr, im; };
struct G4 { CU2 u00, u01, u10, u11; };  // 64 B per gate

__device__ __forceinline__ float2 cmulv(const CU2 u, const float2 a) {
    float2 t;
    asm("v_pk_mul_f32 %0, %1, %2 op_sel:[0,1] op_sel_hi:[1,0]"
        : "=v"(t) : "v"(u.im), "v"(a));
    asm("v_pk_fma_f32 %0, %1, %2, %3"
        : "=v"(t) : "v"(u.rr), "v"(a), "v"(t));
    return t;
}
__device__ __forceinline__ float2 cfmav(const CU2 u, const float2 a, float2 acc) {
    asm("v_pk_fma_f32 %0, %1, %2, %3 op_sel:[0,1,0] op_sel_hi:[1,0,1]"
        : "=v"(acc) : "v"(u.im), "v"(a), "v"(acc));
    asm("v_pk_fma_f32 %0, %1, %2, %3"
        : "=v"(acc) : "v"(u.rr), "v"(a), "v"(acc));
    return acc;
}

// ================= gates =================
template <int E, int B>
__device__ __forceinline__ void rotg(float2 (&a)[4], int lane, const G4& gg) {
    const G4 g = gg;  // broadcast ds_read_b128 x4
    constexpr int k = regPos(E, B);
    if constexpr (k >= 0) {
        constexpr int m = 1 << k;
#pragma unroll
        for (int r = 0; r < 4; ++r)
            if (!(r & m)) {
                const float2 a0 = a[r], a1 = a[r | m];
                a[r]     = cfmav(g.u01, a1, cmulv(g.u00, a0));
                a[r | m] = cfmav(g.u10, a0, cmulv(g.u11, a1));
            }
    } else {
        constexpr int j = lanePos(E, B);
        static_assert(j >= 0, "rot on wave bit");
        const bool hi = (lane >> j) & 1;
        CU2 co, cp;
        co.rr = hi ? g.u11.rr : g.u00.rr;  co.im = hi ? g.u11.im : g.u00.im;
        cp.rr = hi ? g.u10.rr : g.u01.rr;  cp.im = hi ? g.u10.im : g.u01.im;
#pragma unroll
        for (int r = 0; r < 4; ++r) {
            float2 p;
            p.x = lx<j>(a[r].x);
            p.y = lx<j>(a[r].y);
            a[r] = cfmav(cp, p, cmulv(co, a[r]));
        }
    }
}

template <int E, int C, int T>
__device__ __forceinline__ void cnot(float2 (&a)[4], int lane, int wv) {
    constexpr int kc = regPos(E, C), jc = lanePos(E, C), mc = wavePos(E, C);
    constexpr int kt = regPos(E, T), jt = lanePos(E, T);
    static_assert(wavePos(E, T) < 0, "cnot target on wave bit");
    if constexpr (kt >= 0) {
        constexpr int mt = 1 << kt;
        if constexpr (kc >= 0) {
            constexpr int mcb = 1 << kc;
#pragma unroll
            for (int r = 0; r < 4; ++r)
                if ((r & mcb) && !(r & mt)) { float2 t = a[r]; a[r] = a[r | mt]; a[r | mt] = t; }
        } else if constexpr (jc >= 0) {
            const bool p = (lane >> jc) & 1;
#pragma unroll
            for (int r = 0; r < 4; ++r)
                if (!(r & mt)) {
                    const float2 lo = a[r], hi = a[r | mt];
                    a[r].x = p ? hi.x : lo.x;       a[r].y = p ? hi.y : lo.y;
                    a[r | mt].x = p ? lo.x : hi.x;  a[r | mt].y = p ? lo.y : hi.y;
                }
        } else {
            if ((wv >> mc) & 1) {
#pragma unroll
                for (int r = 0; r < 4; ++r)
                    if (!(r & mt)) { float2 t = a[r]; a[r] = a[r | mt]; a[r | mt] = t; }
            }
        }
    } else {  // target on lane bit jt
        if constexpr (kc >= 0) {
            constexpr int mcb = 1 << kc;
#pragma unroll
            for (int r = 0; r < 4; ++r)
                if (r & mcb) { a[r].x = lx<jt>(a[r].x); a[r].y = lx<jt>(a[r].y); }
        } else if constexpr (jc >= 0) {
            const bool p = (lane >> jc) & 1;
#pragma unroll
            for (int r = 0; r < 4; ++r) {
                const float px = lx<jt>(a[r].x), py = lx<jt>(a[r].y);
                a[r].x = p ? px : a[r].x;  a[r].y = p ? py : a[r].y;
            }
        } else {
            if ((wv >> mc) & 1) {
#pragma unroll
                for (int r = 0; r < 4; ++r) { a[r].x = lx<jt>(a[r].x); a[r].y = lx<jt>(a[r].y); }
            }
        }
    }
}

// remap: write mapping PE (linear swizzled slots), barrier, read mapping CE.
// No trailing barrier: caller alternates between two LDS buffers (WAR separated
// by the NEXT remap's barrier).
template <int PE, int CE>
__device__ __forceinline__ void remap(float2 (&a)[4], int lane, int wv, float2* st) {
    const int wbase = swzl((wv << 8) | (lane << 2));
#pragma unroll
    for (int r = 0; r < 4; ++r) st[wbase ^ r] = a[r];
    __syncthreads();
    const int rbase = swzl(slotOf(PE, stateOf(CE, wv, lane, 0)));
#pragma unroll
    for (int r = 0; r < 4; ++r) {
        const int d = swzl(slotOf(PE, stateOf(CE, 0, 0, r)));  // compile-time folds
        a[r] = st[rbase ^ d];
    }
}

// ============ measurement masks: ring3 (CNOT(w,w+3)) absorbed, GF(2)-derived ============
constexpr int MASKW[12] = {0x124, 0x092, 0x049, 0x900, 0x480, 0x240,
                           0x920, 0x490, 0x248, 0x924, 0x492, 0x249};
constexpr int rmOf(int w) { int v = 0; for (int k = 0; k < 2; ++k) v |= ((MASKW[w] >> MP[3].rb[k]) & 1) << k; return v; }
constexpr int lmOf(int w) { int v = 0; for (int j = 0; j < 6; ++j) v |= ((MASKW[w] >> MP[3].lb[j]) & 1) << j; return v; }
constexpr int wmOf(int w) { int v = 0; for (int m = 0; m < 4; ++m) v |= ((MASKW[w] >> MP[3].wb[m]) & 1) << m; return v; }
constexpr int RMa[12] = {rmOf(0),rmOf(1),rmOf(2),rmOf(3),rmOf(4),rmOf(5),rmOf(6),rmOf(7),rmOf(8),rmOf(9),rmOf(10),rmOf(11)};
constexpr int LMa[12] = {lmOf(0),lmOf(1),lmOf(2),lmOf(3),lmOf(4),lmOf(5),lmOf(6),lmOf(7),lmOf(8),lmOf(9),lmOf(10),lmOf(11)};
constexpr int WMa[12] = {wmOf(0),wmOf(1),wmOf(2),wmOf(3),wmOf(4),wmOf(5),wmOf(6),wmOf(7),wmOf(8),wmOf(9),wmOf(10),wmOf(11)};

// ================= gate construction helpers =================
__device__ __forceinline__ void buildRot(int g, const float* __restrict__ q_w, float R[8]) {
    const float phi = q_w[3 * g], th = q_w[3 * g + 1], om = q_w[3 * g + 2];
    float sth, cth, sa, ca, sb, cb;
    sincosf(0.5f * th, &sth, &cth);
    sincosf(0.5f * (phi + om), &sa, &ca);
    sincosf(0.5f * (phi - om), &sb, &cb);
    R[0] = cth * ca;  R[1] = -cth * sa;   // U00
    R[2] = -sth * cb; R[3] = -sth * sb;   // U01
    R[4] = sth * cb;  R[5] = -sth * sb;   // U10
    R[6] = cth * ca;  R[7] = cth * sa;    // U11
}
__device__ __forceinline__ void storeGate(G4* dst, const float R[8]) {
    G4 g;
    g.u00.rr = make_float2(R[0], R[0]); g.u00.im = make_float2(-R[1], R[1]);
    g.u01.rr = make_float2(R[2], R[2]); g.u01.im = make_float2(-R[3], R[3]);
    g.u10.rr = make_float2(R[4], R[4]); g.u10.im = make_float2(-R[5], R[5]);
    g.u11.rr = make_float2(R[6], R[6]); g.u11.im = make_float2(-R[7], R[7]);
    *dst = g;
}

// ================= kernel =================
__global__ __launch_bounds__(1024, 8) void hybrid_r9(
    const float* __restrict__ x, const float* __restrict__ proj_w,
    const float* __restrict__ proj_b, const float* __restrict__ ln_w,
    const float* __restrict__ ln_b, const float* __restrict__ q_w,
    const float* __restrict__ h1_w, const float* __restrict__ h1_b,
    const float* __restrict__ h2_w, const float* __restrict__ h2_b,
    float* __restrict__ out) {
    __shared__ float2 st[2][4096];  // 64 KB double-buffered remap
    __shared__ G4 rotU[36];
    __shared__ float hbuf[12];
    __shared__ float red[12 * 16];
    __shared__ float z1[256];
    __shared__ float qz[12];

    const int b = blockIdx.x;
    const int tid = threadIdx.x;   // 0..1023
    const int lane = tid & 63;
    const int wv = tid >> 6;       // 0..15

    // ---- 1a. projection on waves 0..11 (wave j -> output j) ----
    if (wv < 12) {
        const float* xr = x + (size_t)b * D_IN;
        const float* wr = proj_w + wv * D_IN;
        float s = 0.f;
#pragma unroll
        for (int k = 0; k < 12; ++k) s += xr[lane + k * 64] * wr[lane + k * 64];
        s = waveRed(s);
        if (lane == 0) hbuf[wv] = tanhf(s + proj_b[wv]);
    }
    // ---- 1b. shared gates 12..35 built concurrently on wave 12 ----
    if (tid >= 768 && tid < 792) {
        const int g = tid - 768 + 12;
        float R[8];
        buildRot(g, q_w, R);
        storeGate(&rotU[g], R);
    }
    __syncthreads();

    // ---- 2. fused L0 gates: one per wave (lane 0 of waves 0..11) ----
    if (lane == 0 && wv < 12) {
        float mu = 0.f;
#pragma unroll
        for (int k = 0; k < 12; ++k) mu += hbuf[k];
        mu *= (1.f / 12.f);
        float var = 0.f;
#pragma unroll
        for (int k = 0; k < 12; ++k) { const float d = hbuf[k] - mu; var += d * d; }
        var *= (1.f / 12.f);
        const float inv = 1.f / sqrtf(var + 1e-5f);
        const float ang = (hbuf[wv] - mu) * inv * ln_w[wv] + ln_b[wv];
        float sy, cy;
        sincosf(0.5f * ang, &sy, &cy);
        float R[8];
        buildRot(wv, q_w, R);
        float M[8];
        M[0] = R[0] * cy + R[2] * sy;  M[1] = R[1] * cy + R[3] * sy;
        M[2] = -R[0] * sy + R[2] * cy; M[3] = -R[1] * sy + R[3] * cy;
        M[4] = R[4] * cy + R[6] * sy;  M[5] = R[5] * cy + R[7] * sy;
        M[6] = -R[4] * sy + R[6] * cy; M[7] = -R[5] * sy + R[7] * cy;
        storeGate(&rotU[wv], M);
    }
    __syncthreads();

    // ---- 3. state |0..0>: E0 maps i=0 -> wv0,lane0,r0 ----
    float2 a[4];
#pragma unroll
    for (int r = 0; r < 4; ++r) a[r] = make_float2(0.f, 0.f);
    if (tid == 0) a[0].x = 1.f;

    // ---- 4. circuit ----
    // E0: reg={10,11} lane={4..9} wave={0,1,2,3}
    rotg<0, 11>(a, lane, rotU[0]); rotg<0, 10>(a, lane, rotU[1]); rotg<0, 9>(a, lane, rotU[2]);
    rotg<0, 8>(a, lane, rotU[3]);  rotg<0, 7>(a, lane, rotU[4]);  rotg<0, 6>(a, lane, rotU[5]);
    rotg<0, 5>(a, lane, rotU[6]);  rotg<0, 4>(a, lane, rotU[7]);
    cnot<0, 11, 10>(a, lane, wv); cnot<0, 10, 9>(a, lane, wv); cnot<0, 9, 8>(a, lane, wv);
    cnot<0, 8, 7>(a, lane, wv);   cnot<0, 7, 6>(a, lane, wv);  cnot<0, 6, 5>(a, lane, wv);
    cnot<0, 5, 4>(a, lane, wv);
    remap<0, 1>(a, lane, wv, st[0]);
    // E1: reg={0,1} lane={2,3,8,9,10,11} wave={4,5,6,7}
    rotg<1, 3>(a, lane, rotU[8]); rotg<1, 2>(a, lane, rotU[9]);
    rotg<1, 1>(a, lane, rotU[10]); rotg<1, 0>(a, lane, rotU[11]);
    cnot<1, 4, 3>(a, lane, wv); cnot<1, 3, 2>(a, lane, wv); cnot<1, 2, 1>(a, lane, wv);
    cnot<1, 1, 0>(a, lane, wv); cnot<1, 0, 11>(a, lane, wv);
    rotg<1, 11>(a, lane, rotU[12]); rotg<1, 10>(a, lane, rotU[13]);
    rotg<1, 9>(a, lane, rotU[14]);  rotg<1, 8>(a, lane, rotU[15]);
    rotg<1, 3>(a, lane, rotU[20]);  rotg<1, 2>(a, lane, rotU[21]);
    rotg<1, 1>(a, lane, rotU[22]);  rotg<1, 0>(a, lane, rotU[23]);
    cnot<1, 11, 9>(a, lane, wv); cnot<1, 10, 8>(a, lane, wv);
    remap<1, 2>(a, lane, wv, st[1]);
    // E2: reg={6,7} lane={5,4,2,3,0,1} wave={8,9,10,11}
    rotg<2, 7>(a, lane, rotU[16]); rotg<2, 6>(a, lane, rotU[17]);
    rotg<2, 5>(a, lane, rotU[18]); rotg<2, 4>(a, lane, rotU[19]);
    cnot<2, 9, 7>(a, lane, wv); cnot<2, 8, 6>(a, lane, wv); cnot<2, 7, 5>(a, lane, wv);
    cnot<2, 6, 4>(a, lane, wv); cnot<2, 5, 3>(a, lane, wv); cnot<2, 4, 2>(a, lane, wv);
    cnot<2, 3, 1>(a, lane, wv); cnot<2, 2, 0>(a, lane, wv);
    rotg<2, 7>(a, lane, rotU[28]); rotg<2, 6>(a, lane, rotU[29]);
    rotg<2, 5>(a, lane, rotU[30]); rotg<2, 4>(a, lane, rotU[31]);
    rotg<2, 3>(a, lane, rotU[32]); rotg<2, 2>(a, lane, rotU[33]);
    remap<2, 3>(a, lane, wv, st[0]);
    // E3: reg={0,1} lane={2,3,8,9,10,11} wave={4,5,6,7}
    cnot<3, 1, 11>(a, lane, wv); cnot<3, 0, 10>(a, lane, wv);
    rotg<3, 11>(a, lane, rotU[24]); rotg<3, 10>(a, lane, rotU[25]);
    rotg<3, 9>(a, lane, rotU[26]);  rotg<3, 8>(a, lane, rotU[27]);
    rotg<3, 1>(a, lane, rotU[34]);  rotg<3, 0>(a, lane, rotU[35]);
    // ring3 absorbed into measurement masks.

    // ---- 5. measurement ----
    {
        const float p0 = a[0].x * a[0].x + a[0].y * a[0].y;
        const float p1 = a[1].x * a[1].x + a[1].y * a[1].y;
        const float p2 = a[2].x * a[2].x + a[2].y * a[2].y;
        const float p3 = a[3].x * a[3].x + a[3].y * a[3].y;
        const float s[4] = {p0 + p1 + p2 + p3, p0 - p1 + p2 - p3,
                            p0 + p1 - p2 - p3, p0 - p1 - p2 + p3};
#pragma unroll
        for (int w = 0; w < 12; ++w) {
            const int sgn = (__popc(lane & LMa[w]) + __popc(wv & WMa[w])) & 1;
            float v = sgn ? -s[RMa[w]] : s[RMa[w]];
            v = waveRed(v);
            if (lane == 0) red[w * 16 + wv] = v;
        }
    }
    __syncthreads();
    if (tid < 12) {
        float q = 0.f;
#pragma unroll
        for (int m = 0; m < 16; ++m) q += red[tid * 16 + m];
        qz[tid] = q;
    }
    __syncthreads();

    // ---- 6. MLP hidden: relu(q @ h1_w.T + h1_b) ----
    if (tid < 256) {
        float s = h1_b[tid];
#pragma unroll
        for (int k = 0; k < 12; ++k) s += qz[k] * h1_w[tid * 12 + k];
        z1[tid] = fmaxf(s, 0.f);
    }
    __syncthreads();

    // ---- 7. out = z1 @ h2_w.T + h2_b : waves 0..13, 2 outputs each ----
    if (wv < 14) {
#pragma unroll
        for (int jj = 0; jj < 2; ++jj) {
            const int j = wv * 2 + jj;
            const float* wr = h2_w + j * 256;
            float s = 0.f;
#pragma unroll
            for (int k = 0; k < 4; ++k) s += z1[lane + k * 64] * wr[lane + k * 64];
            s = waveRed(s);
            if (lane == 0) out[(size_t)b * NLAB + j] = s + h2_b[j];
        }
    }
}

extern "C" void kernel_launch(void* const* d_in, const int* in_sizes, int n_in,
                              void* d_out, int out_size, void* d_ws, size_t ws_size,
                              hipStream_t stream) {
    const float* x      = (const float*)d_in[0];
    const float* proj_w = (const float*)d_in[1];
    const float* proj_b = (const float*)d_in[2];
    const float* ln_w   = (const float*)d_in[3];
    const float* ln_b   = (const float*)d_in[4];
    const float* q_w    = (const float*)d_in[5];
    const float* h1_w   = (const float*)d_in[6];
    const float* h1_b   = (const float*)d_in[7];
    const float* h2_w   = (const float*)d_in[8];
    const float* h2_b   = (const float*)d_in[9];
    float* out = (float*)d_out;

    const int B = in_sizes[0] / D_IN;  // 512
    hybrid_r9<<<dim3(B), dim3(1024), 0, stream>>>(x, proj_w, proj_b, ln_w, ln_b,
                                                  q_w, h1_w, h1_b, h2_w, h2_b, out);
}

// Round 11
// 32.627 us; speedup vs baseline: 1.2564x; 1.2564x over previous
//
#include <hip/hip_runtime.h>
#include <math.h>

#define D_IN 768
#define NLAB 28

// ================= bit-location maps per epoch =================
struct Map { int rb[2]; int lb[6]; int wb[4]; };
constexpr Map MP[4] = {
    {{10, 11}, {4, 5, 6, 7, 8, 9}, {0, 1, 2, 3}},
    {{0, 1}, {2, 3, 8, 9, 10, 11}, {4, 5, 6, 7}},
    {{6, 7}, {5, 4, 2, 3, 0, 1}, {8, 9, 10, 11}},   // lb permuted: hot bits 5,4 on DPP lanes
    {{0, 1}, {2, 3, 8, 9, 10, 11}, {4, 5, 6, 7}},
};
constexpr int regPos(int e, int b) { for (int k = 0; k < 2; ++k) if (MP[e].rb[k] == b) return k; return -1; }
constexpr int lanePos(int e, int b) { for (int j = 0; j < 6; ++j) if (MP[e].lb[j] == b) return j; return -1; }
constexpr int wavePos(int e, int b) { for (int m = 0; m < 4; ++m) if (MP[e].wb[m] == b) return m; return -1; }

constexpr int stateOf(int e, int wv, int lane, int r) {
    int i = 0;
    for (int k = 0; k < 2; ++k) i |= ((r >> k) & 1) << MP[e].rb[k];
    for (int j = 0; j < 6; ++j) i |= ((lane >> j) & 1) << MP[e].lb[j];
    for (int m = 0; m < 4; ++m) i |= ((wv >> m) & 1) << MP[e].wb[m];
    return i;
}
constexpr int slotOf(int e, int i) {
    int r = 0, ln = 0, wv = 0;
    for (int k = 0; k < 2; ++k) r |= ((i >> MP[e].rb[k]) & 1) << k;
    for (int j = 0; j < 6; ++j) ln |= ((i >> MP[e].lb[j]) & 1) << j;
    for (int m = 0; m < 4; ++m) wv |= ((i >> MP[e].wb[m]) & 1) << m;
    return (wv << 8) | (ln << 2) | r;
}
constexpr int swzl(int s) { return s ^ (((s >> 4) ^ (s >> 8)) & 15); }  // GF(2)-linear

// ============ cross-lane exchange at distance 2^J — pipe-balanced mix ============
// J0/J1/J3: DPP (VALU). J2: DPP shl/shr pair (VALU, no lgkm dep).
// J4: ds_swizzle, J5: shfl (LDS pipe — co-issues with VALU across 8 waves/SIMD).
template <int J>
__device__ __forceinline__ float lx(float v) {
    if constexpr (J == 0 || J == 1 || J == 3) {
        constexpr int ctrl = (J == 0) ? 0xB1 : (J == 1) ? 0x4E : 0x128;
        return __int_as_float(__builtin_amdgcn_update_dpp(
            0, __float_as_int(v), ctrl, 0xF, 0xF, true));
    } else if constexpr (J == 2) {
        // lanes bit4=0 need i+4 (row_shl:4); bit4=1 need i-4 (row_shr:4)
        const float tshl = __int_as_float(__builtin_amdgcn_update_dpp(
            0, __float_as_int(v), 0x104, 0xF, 0xF, true));
        const float tshr = __int_as_float(__builtin_amdgcn_update_dpp(
            0, __float_as_int(v), 0x114, 0xF, 0xF, true));
        return (threadIdx.x & 4) ? tshr : tshl;
    } else if constexpr (J == 4) {
        return __int_as_float(__builtin_amdgcn_ds_swizzle(__float_as_int(v), 0x401F));
    } else {
        return __shfl_xor(v, 32, 64);
    }
}
__device__ __forceinline__ float waveRed(float v) {
    v += lx<0>(v); v += lx<1>(v); v += lx<2>(v);
    v += lx<3>(v); v += lx<4>(v); v += lx<5>(v);
    return v;
}

// ======= packed-f32 complex helpers: u stored as rr=(ur,ur), im=(-ui,ui) =======
struct CU2 { float2 rr, im; };   // 16 B
struct GP  { CU2 co, cp; };      // 32 B: {own-coef, partner-coef}
struct G4  { GP h[2]; };         // h[0]={u00,u01}, h[1]={u11,u10}

__device__ __forceinline__ float2 cmulv(const CU2 u, const float2 a) {
    float2 t;
    asm("v_pk_mul_f32 %0, %1, %2 op_sel:[0,1] op_sel_hi:[1,0]"
        : "=v"(t) : "v"(u.im), "v"(a));
    asm("v_pk_fma_f32 %0, %1, %2, %3"
        : "=v"(t) : "v"(u.rr), "v"(a), "v"(t));
    return t;
}
__device__ __forceinline__ float2 cfmav(const CU2 u, const float2 a, float2 acc) {
    asm("v_pk_fma_f32 %0, %1, %2, %3 op_sel:[0,1,0] op_sel_hi:[1,0,1]"
        : "=v"(acc) : "v"(u.im), "v"(a), "v"(acc));
    asm("v_pk_fma_f32 %0, %1, %2, %3"
        : "=v"(acc) : "v"(u.rr), "v"(a), "v"(acc));
    return acc;
}

// ================= gates =================
template <int E, int B>
__device__ __forceinline__ void rotg(float2 (&a)[4], int lane, const G4* __restrict__ gp) {
    constexpr int k = regPos(E, B);
    if constexpr (k >= 0) {
        const GP glo = gp->h[0];  // u00, u01
        const GP ghi = gp->h[1];  // u11, u10
        constexpr int m = 1 << k;
#pragma unroll
        for (int r = 0; r < 4; ++r)
            if (!(r & m)) {
                const float2 a0 = a[r], a1 = a[r | m];
                a[r]     = cfmav(glo.cp, a1, cmulv(glo.co, a0));
                a[r | m] = cfmav(ghi.cp, a0, cmulv(ghi.co, a1));
            }
    } else {
        constexpr int j = lanePos(E, B);
        static_assert(j >= 0, "rot on wave bit");
        const int hi = (lane >> j) & 1;
        const GP g = gp->h[hi];   // lane-indexed 32B read: no cndmask chain
#pragma unroll
        for (int r = 0; r < 4; ++r) {
            float2 p;
            p.x = lx<j>(a[r].x);
            p.y = lx<j>(a[r].y);
            a[r] = cfmav(g.cp, p, cmulv(g.co, a[r]));
        }
    }
}

template <int E, int C, int T>
__device__ __forceinline__ void cnot(float2 (&a)[4], int lane, int wv) {
    constexpr int kc = regPos(E, C), jc = lanePos(E, C), mc = wavePos(E, C);
    constexpr int kt = regPos(E, T), jt = lanePos(E, T);
    static_assert(wavePos(E, T) < 0, "cnot target on wave bit");
    if constexpr (kt >= 0) {
        constexpr int mt = 1 << kt;
        if constexpr (kc >= 0) {
            constexpr int mcb = 1 << kc;
#pragma unroll
            for (int r = 0; r < 4; ++r)
                if ((r & mcb) && !(r & mt)) { float2 t = a[r]; a[r] = a[r | mt]; a[r | mt] = t; }
        } else if constexpr (jc >= 0) {
            const bool p = (lane >> jc) & 1;
#pragma unroll
            for (int r = 0; r < 4; ++r)
                if (!(r & mt)) {
                    const float2 lo = a[r], hi = a[r | mt];
                    a[r].x = p ? hi.x : lo.x;       a[r].y = p ? hi.y : lo.y;
                    a[r | mt].x = p ? lo.x : hi.x;  a[r | mt].y = p ? lo.y : hi.y;
                }
        } else {
            if ((wv >> mc) & 1) {
#pragma unroll
                for (int r = 0; r < 4; ++r)
                    if (!(r & mt)) { float2 t = a[r]; a[r] = a[r | mt]; a[r | mt] = t; }
            }
        }
    } else {  // target on lane bit jt
        if constexpr (kc >= 0) {
            constexpr int mcb = 1 << kc;
#pragma unroll
            for (int r = 0; r < 4; ++r)
                if (r & mcb) { a[r].x = lx<jt>(a[r].x); a[r].y = lx<jt>(a[r].y); }
        } else if constexpr (jc >= 0) {
            const bool p = (lane >> jc) & 1;
#pragma unroll
            for (int r = 0; r < 4; ++r) {
                const float px = lx<jt>(a[r].x), py = lx<jt>(a[r].y);
                a[r].x = p ? px : a[r].x;  a[r].y = p ? py : a[r].y;
            }
        } else {
            if ((wv >> mc) & 1) {
#pragma unroll
                for (int r = 0; r < 4; ++r) { a[r].x = lx<jt>(a[r].x); a[r].y = lx<jt>(a[r].y); }
            }
        }
    }
}

// remap: write mapping PE (linear swizzled slots), barrier, read mapping CE.
// No trailing barrier: caller alternates two LDS buffers (WAR separated by the
// next remap's barrier).
template <int PE, int CE>
__device__ __forceinline__ void remap(float2 (&a)[4], int lane, int wv, float2* st) {
    const int wbase = swzl((wv << 8) | (lane << 2));
#pragma unroll
    for (int r = 0; r < 4; ++r) st[wbase ^ r] = a[r];
    __syncthreads();
    const int rbase = swzl(slotOf(PE, stateOf(CE, wv, lane, 0)));
#pragma unroll
    for (int r = 0; r < 4; ++r) {
        const int d = swzl(slotOf(PE, stateOf(CE, 0, 0, r)));  // compile-time folds
        a[r] = st[rbase ^ d];
    }
}

// ============ measurement masks: ring3 (CNOT(w,w+3)) absorbed, GF(2)-derived ============
constexpr int MASKW[12] = {0x124, 0x092, 0x049, 0x900, 0x480, 0x240,
                           0x920, 0x490, 0x248, 0x924, 0x492, 0x249};
constexpr int rmOf(int w) { int v = 0; for (int k = 0; k < 2; ++k) v |= ((MASKW[w] >> MP[3].rb[k]) & 1) << k; return v; }
constexpr int lmOf(int w) { int v = 0; for (int j = 0; j < 6; ++j) v |= ((MASKW[w] >> MP[3].lb[j]) & 1) << j; return v; }
constexpr int wmOf(int w) { int v = 0; for (int m = 0; m < 4; ++m) v |= ((MASKW[w] >> MP[3].wb[m]) & 1) << m; return v; }
constexpr int RMa[12] = {rmOf(0),rmOf(1),rmOf(2),rmOf(3),rmOf(4),rmOf(5),rmOf(6),rmOf(7),rmOf(8),rmOf(9),rmOf(10),rmOf(11)};
constexpr int LMa[12] = {lmOf(0),lmOf(1),lmOf(2),lmOf(3),lmOf(4),lmOf(5),lmOf(6),lmOf(7),lmOf(8),lmOf(9),lmOf(10),lmOf(11)};
constexpr int WMa[12] = {wmOf(0),wmOf(1),wmOf(2),wmOf(3),wmOf(4),wmOf(5),wmOf(6),wmOf(7),wmOf(8),wmOf(9),wmOf(10),wmOf(11)};

// ================= gate construction helpers =================
__device__ __forceinline__ void buildRot(int g, const float* __restrict__ q_w, float R[8]) {
    const float phi = q_w[3 * g], th = q_w[3 * g + 1], om = q_w[3 * g + 2];
    float sth, cth, sa, ca, sb, cb;
    sincosf(0.5f * th, &sth, &cth);
    sincosf(0.5f * (phi + om), &sa, &ca);
    sincosf(0.5f * (phi - om), &sb, &cb);
    R[0] = cth * ca;  R[1] = -cth * sa;   // U00
    R[2] = -sth * cb; R[3] = -sth * sb;   // U01
    R[4] = sth * cb;  R[5] = -sth * sb;   // U10
    R[6] = cth * ca;  R[7] = cth * sa;    // U11
}
__device__ __forceinline__ void storeGate(G4* dst, const float R[8]) {
    G4 g;
    g.h[0].co.rr = make_float2(R[0], R[0]); g.h[0].co.im = make_float2(-R[1], R[1]);  // u00
    g.h[0].cp.rr = make_float2(R[2], R[2]); g.h[0].cp.im = make_float2(-R[3], R[3]);  // u01
    g.h[1].co.rr = make_float2(R[6], R[6]); g.h[1].co.im = make_float2(-R[7], R[7]);  // u11
    g.h[1].cp.rr = make_float2(R[4], R[4]); g.h[1].cp.im = make_float2(-R[5], R[5]);  // u10
    *dst = g;
}

// ================= kernel =================
__global__ __launch_bounds__(1024, 8) void hybrid_r11(
    const float* __restrict__ x, const float* __restrict__ proj_w,
    const float* __restrict__ proj_b, const float* __restrict__ ln_w,
    const float* __restrict__ ln_b, const float* __restrict__ q_w,
    const float* __restrict__ h1_w, const float* __restrict__ h1_b,
    const float* __restrict__ h2_w, const float* __restrict__ h2_b,
    float* __restrict__ out) {
    __shared__ float2 st[2][4096];  // 64 KB double-buffered remap
    __shared__ G4 rotU[36];
    __shared__ float hbuf[12];
    __shared__ float red[12 * 16];
    __shared__ float z1[256];
    __shared__ float qz[12];

    const int b = blockIdx.x;
    const int tid = threadIdx.x;   // 0..1023
    const int lane = tid & 63;
    const int wv = tid >> 6;       // 0..15

    // ---- 1a. projection on waves 0..11 (wave j -> output j) ----
    if (wv < 12) {
        const float* xr = x + (size_t)b * D_IN;
        const float* wr = proj_w + wv * D_IN;
        float s = 0.f;
#pragma unroll
        for (int k = 0; k < 12; ++k) s += xr[lane + k * 64] * wr[lane + k * 64];
        s = waveRed(s);
        if (lane == 0) hbuf[wv] = tanhf(s + proj_b[wv]);
    }
    // ---- 1b. shared gates 12..35 built concurrently on wave 12 ----
    if (tid >= 768 && tid < 792) {
        const int g = tid - 768 + 12;
        float R[8];
        buildRot(g, q_w, R);
        storeGate(&rotU[g], R);
    }
    __syncthreads();

    // ---- 2. fused L0 gates: one per wave (lane 0 of waves 0..11) ----
    if (lane == 0 && wv < 12) {
        float mu = 0.f;
#pragma unroll
        for (int k = 0; k < 12; ++k) mu += hbuf[k];
        mu *= (1.f / 12.f);
        float var = 0.f;
#pragma unroll
        for (int k = 0; k < 12; ++k) { const float d = hbuf[k] - mu; var += d * d; }
        var *= (1.f / 12.f);
        const float inv = 1.f / sqrtf(var + 1e-5f);
        const float ang = (hbuf[wv] - mu) * inv * ln_w[wv] + ln_b[wv];
        float sy, cy;
        sincosf(0.5f * ang, &sy, &cy);
        float R[8];
        buildRot(wv, q_w, R);
        float M[8];
        M[0] = R[0] * cy + R[2] * sy;  M[1] = R[1] * cy + R[3] * sy;
        M[2] = -R[0] * sy + R[2] * cy; M[3] = -R[1] * sy + R[3] * cy;
        M[4] = R[4] * cy + R[6] * sy;  M[5] = R[5] * cy + R[7] * sy;
        M[6] = -R[4] * sy + R[6] * cy; M[7] = -R[5] * sy + R[7] * cy;
        storeGate(&rotU[wv], M);
    }
    __syncthreads();

    // ---- 3. state |0..0>: E0 maps i=0 -> wv0,lane0,r0 ----
    float2 a[4];
#pragma unroll
    for (int r = 0; r < 4; ++r) a[r] = make_float2(0.f, 0.f);
    if (tid == 0) a[0].x = 1.f;

    // ---- 4. circuit ----
    // E0: reg={10,11} lane={4..9} wave={0,1,2,3}
    rotg<0, 11>(a, lane, rotU + 0); rotg<0, 10>(a, lane, rotU + 1); rotg<0, 9>(a, lane, rotU + 2);
    rotg<0, 8>(a, lane, rotU + 3);  rotg<0, 7>(a, lane, rotU + 4);  rotg<0, 6>(a, lane, rotU + 5);
    rotg<0, 5>(a, lane, rotU + 6);  rotg<0, 4>(a, lane, rotU + 7);
    cnot<0, 11, 10>(a, lane, wv); cnot<0, 10, 9>(a, lane, wv); cnot<0, 9, 8>(a, lane, wv);
    cnot<0, 8, 7>(a, lane, wv);   cnot<0, 7, 6>(a, lane, wv);  cnot<0, 6, 5>(a, lane, wv);
    cnot<0, 5, 4>(a, lane, wv);
    remap<0, 1>(a, lane, wv, st[0]);
    // E1: reg={0,1} lane={2,3,8,9,10,11} wave={4,5,6,7}
    rotg<1, 3>(a, lane, rotU + 8); rotg<1, 2>(a, lane, rotU + 9);
    rotg<1, 1>(a, lane, rotU + 10); rotg<1, 0>(a, lane, rotU + 11);
    cnot<1, 4, 3>(a, lane, wv); cnot<1, 3, 2>(a, lane, wv); cnot<1, 2, 1>(a, lane, wv);
    cnot<1, 1, 0>(a, lane, wv); cnot<1, 0, 11>(a, lane, wv);
    rotg<1, 11>(a, lane, rotU + 12); rotg<1, 10>(a, lane, rotU + 13);
    rotg<1, 9>(a, lane, rotU + 14);  rotg<1, 8>(a, lane, rotU + 15);
    rotg<1, 3>(a, lane, rotU + 20);  rotg<1, 2>(a, lane, rotU + 21);
    rotg<1, 1>(a, lane, rotU + 22);  rotg<1, 0>(a, lane, rotU + 23);
    cnot<1, 11, 9>(a, lane, wv); cnot<1, 10, 8>(a, lane, wv);
    remap<1, 2>(a, lane, wv, st[1]);
    // E2: reg={6,7} lane={5,4,2,3,0,1} wave={8,9,10,11}
    rotg<2, 7>(a, lane, rotU + 16); rotg<2, 6>(a, lane, rotU + 17);
    rotg<2, 5>(a, lane, rotU + 18); rotg<2, 4>(a, lane, rotU + 19);
    cnot<2, 9, 7>(a, lane, wv); cnot<2, 8, 6>(a, lane, wv); cnot<2, 7, 5>(a, lane, wv);
    cnot<2, 6, 4>(a, lane, wv); cnot<2, 5, 3>(a, lane, wv); cnot<2, 4, 2>(a, lane, wv);
    cnot<2, 3, 1>(a, lane, wv); cnot<2, 2, 0>(a, lane, wv);
    rotg<2, 7>(a, lane, rotU + 28); rotg<2, 6>(a, lane, rotU + 29);
    rotg<2, 5>(a, lane, rotU + 30); rotg<2, 4>(a, lane, rotU + 31);
    rotg<2, 3>(a, lane, rotU + 32); rotg<2, 2>(a, lane, rotU + 33);
    remap<2, 3>(a, lane, wv, st[0]);
    // E3: reg={0,1} lane={2,3,8,9,10,11} wave={4,5,6,7}
    cnot<3, 1, 11>(a, lane, wv); cnot<3, 0, 10>(a, lane, wv);
    rotg<3, 11>(a, lane, rotU + 24); rotg<3, 10>(a, lane, rotU + 25);
    rotg<3, 9>(a, lane, rotU + 26);  rotg<3, 8>(a, lane, rotU + 27);
    rotg<3, 1>(a, lane, rotU + 34);  rotg<3, 0>(a, lane, rotU + 35);
    // ring3 absorbed into measurement masks.

    // ---- 5. measurement ----
    {
        const float p0 = a[0].x * a[0].x + a[0].y * a[0].y;
        const float p1 = a[1].x * a[1].x + a[1].y * a[1].y;
        const float p2 = a[2].x * a[2].x + a[2].y * a[2].y;
        const float p3 = a[3].x * a[3].x + a[3].y * a[3].y;
        const float s[4] = {p0 + p1 + p2 + p3, p0 - p1 + p2 - p3,
                            p0 + p1 - p2 - p3, p0 - p1 - p2 + p3};
#pragma unroll
        for (int w = 0; w < 12; ++w) {
            const int sgn = (__popc(lane & LMa[w]) + __popc(wv & WMa[w])) & 1;
            float v = sgn ? -s[RMa[w]] : s[RMa[w]];
            v = waveRed(v);
            if (lane == 0) red[w * 16 + wv] = v;
        }
    }
    __syncthreads();
    if (tid < 12) {
        float q = 0.f;
#pragma unroll
        for (int m = 0; m < 16; ++m) q += red[tid * 16 + m];
        qz[tid] = q;
    }
    __syncthreads();

    // ---- 6. MLP hidden: relu(q @ h1_w.T + h1_b) ----
    if (tid < 256) {
        float s = h1_b[tid];
#pragma unroll
        for (int k = 0; k < 12; ++k) s += qz[k] * h1_w[tid * 12 + k];
        z1[tid] = fmaxf(s, 0.f);
    }
    __syncthreads();

    // ---- 7. out = z1 @ h2_w.T + h2_b : waves 0..13, 2 outputs each ----
    if (wv < 14) {
#pragma unroll
        for (int jj = 0; jj < 2; ++jj) {
            const int j = wv * 2 + jj;
            const float* wr = h2_w + j * 256;
            float s = 0.f;
#pragma unroll
            for (int k = 0; k < 4; ++k) s += z1[lane + k * 64] * wr[lane + k * 64];
            s = waveRed(s);
            if (lane == 0) out[(size_t)b * NLAB + j] = s + h2_b[j];
        }
    }
}

extern "C" void kernel_launch(void* const* d_in, const int* in_sizes, int n_in,
                              void* d_out, int out_size, void* d_ws, size_t ws_size,
                              hipStream_t stream) {
    const float* x      = (const float*)d_in[0];
    const float* proj_w = (const float*)d_in[1];
    const float* proj_b = (const float*)d_in[2];
    const float* ln_w   = (const float*)d_in[3];
    const float* ln_b   = (const float*)d_in[4];
    const float* q_w    = (const float*)d_in[5];
    const float* h1_w   = (const float*)d_in[6];
    const float* h1_b   = (const float*)d_in[7];
    const float* h2_w   = (const float*)d_in[8];
    const float* h2_b   = (const float*)d_in[9];
    float* out = (float*)d_out;

    const int B = in_sizes[0] / D_IN;  // 512
    hybrid_r11<<<dim3(B), dim3(1024), 0, stream>>>(x, proj_w, proj_b, ln_w, ln_b,
                                                   q_w, h1_w, h1_b, h2_w, h2_b, out);
}

// Round 15
// 29.720 us; speedup vs baseline: 1.3793x; 1.0978x over previous
//
#include <hip/hip_runtime.h>
#include <math.h>

#define D_IN 768
#define NLAB 28

// ================= bit-location maps per epoch =================
struct Map { int rb[2]; int lb[6]; int wb[4]; };
constexpr Map MP[4] = {
    {{10, 11}, {4, 5, 6, 7, 8, 9}, {0, 1, 2, 3}},
    {{0, 1}, {2, 3, 8, 9, 10, 11}, {4, 5, 6, 7}},
    {{6, 7}, {5, 4, 2, 3, 0, 1}, {8, 9, 10, 11}},   // lb permuted: hot bits 5,4 on DPP lanes
    {{0, 1}, {2, 3, 8, 9, 10, 11}, {4, 5, 6, 7}},
};
constexpr int regPos(int e, int b) { for (int k = 0; k < 2; ++k) if (MP[e].rb[k] == b) return k; return -1; }
constexpr int lanePos(int e, int b) { for (int j = 0; j < 6; ++j) if (MP[e].lb[j] == b) return j; return -1; }
constexpr int wavePos(int e, int b) { for (int m = 0; m < 4; ++m) if (MP[e].wb[m] == b) return m; return -1; }

constexpr int stateOf(int e, int wv, int lane, int r) {
    int i = 0;
    for (int k = 0; k < 2; ++k) i |= ((r >> k) & 1) << MP[e].rb[k];
    for (int j = 0; j < 6; ++j) i |= ((lane >> j) & 1) << MP[e].lb[j];
    for (int m = 0; m < 4; ++m) i |= ((wv >> m) & 1) << MP[e].wb[m];
    return i;
}
constexpr int slotOf(int e, int i) {
    int r = 0, ln = 0, wv = 0;
    for (int k = 0; k < 2; ++k) r |= ((i >> MP[e].rb[k]) & 1) << k;
    for (int j = 0; j < 6; ++j) ln |= ((i >> MP[e].lb[j]) & 1) << j;
    for (int m = 0; m < 4; ++m) wv |= ((i >> MP[e].wb[m]) & 1) << m;
    return (wv << 8) | (ln << 2) | r;
}
constexpr int swzl(int s) { return s ^ (((s >> 4) ^ (s >> 8)) & 15); }  // GF(2)-linear

// ============ cross-lane exchange at distance 2^J — pipe-balanced mix ============
// J0/J1/J3: DPP (VALU). J2/J4: ds_swizzle (LDS pipe, 1 op). J5: shfl (LDS pipe).
template <int J>
__device__ __forceinline__ float lx(float v) {
    if constexpr (J == 0 || J == 1 || J == 3) {
        // xor1: quad_perm[1,0,3,2]=0xB1; xor2: quad_perm[2,3,0,1]=0x4E; xor8: row_ror:8=0x128
        constexpr int ctrl = (J == 0) ? 0xB1 : (J == 1) ? 0x4E : 0x128;
        return __int_as_float(__builtin_amdgcn_update_dpp(
            0, __float_as_int(v), ctrl, 0xF, 0xF, true));
    } else if constexpr (J == 2 || J == 4) {
        constexpr int off = (J == 2) ? 0x101F : 0x401F;  // BitMode xor4 / xor16
        return __int_as_float(__builtin_amdgcn_ds_swizzle(__float_as_int(v), off));
    } else {
        return __shfl_xor(v, 32, 64);
    }
}
__device__ __forceinline__ float waveRed(float v) {
    v += lx<0>(v); v += lx<1>(v); v += lx<2>(v);
    v += lx<3>(v); v += lx<4>(v); v += lx<5>(v);
    return v;
}
// full 64-point Walsh-Hadamard: lane L ends with sum_l (-1)^{popc(L&l)} v(l)
__device__ __forceinline__ float wht64(float v, int lane) {
    { const float t = lx<0>(v); v = (lane & 1)  ? (t - v) : (v + t); }
    { const float t = lx<1>(v); v = (lane & 2)  ? (t - v) : (v + t); }
    { const float t = lx<2>(v); v = (lane & 4)  ? (t - v) : (v + t); }
    { const float t = lx<3>(v); v = (lane & 8)  ? (t - v) : (v + t); }
    { const float t = lx<4>(v); v = (lane & 16) ? (t - v) : (v + t); }
    { const float t = lx<5>(v); v = (lane & 32) ? (t - v) : (v + t); }
    return v;
}

// ======= packed-f32 complex helpers: u stored as rr=(ur,ur), im=(-ui,ui) =======
struct CU2 { float2 rr, im; };   // 16 B
struct GP  { CU2 co, cp; };      // 32 B: {own-coef, partner-coef}
struct G4  { GP h[2]; };         // h[0]={u00,u01}, h[1]={u11,u10}

__device__ __forceinline__ float2 cmulv(const CU2 u, const float2 a) {
    float2 t;
    asm("v_pk_mul_f32 %0, %1, %2 op_sel:[0,1] op_sel_hi:[1,0]"
        : "=v"(t) : "v"(u.im), "v"(a));
    asm("v_pk_fma_f32 %0, %1, %2, %3"
        : "=v"(t) : "v"(u.rr), "v"(a), "v"(t));
    return t;
}
__device__ __forceinline__ float2 cfmav(const CU2 u, const float2 a, float2 acc) {
    asm("v_pk_fma_f32 %0, %1, %2, %3 op_sel:[0,1,0] op_sel_hi:[1,0,1]"
        : "=v"(acc) : "v"(u.im), "v"(a), "v"(acc));
    asm("v_pk_fma_f32 %0, %1, %2, %3"
        : "=v"(acc) : "v"(u.rr), "v"(a), "v"(acc));
    return acc;
}

// ================= gates =================
template <int E, int B>
__device__ __forceinline__ void rotg(float2 (&a)[4], int lane, const G4* __restrict__ gp) {
    constexpr int k = regPos(E, B);
    if constexpr (k >= 0) {
        const GP glo = gp->h[0];  // u00, u01
        const GP ghi = gp->h[1];  // u11, u10
        constexpr int m = 1 << k;
#pragma unroll
        for (int r = 0; r < 4; ++r)
            if (!(r & m)) {
                const float2 a0 = a[r], a1 = a[r | m];
                a[r]     = cfmav(glo.cp, a1, cmulv(glo.co, a0));
                a[r | m] = cfmav(ghi.cp, a0, cmulv(ghi.co, a1));
            }
    } else {
        constexpr int j = lanePos(E, B);
        static_assert(j >= 0, "rot on wave bit");
        const int hi = (lane >> j) & 1;
        const GP g = gp->h[hi];   // lane-indexed 32B read: no cndmask chain
#pragma unroll
        for (int r = 0; r < 4; ++r) {
            float2 p;
            p.x = lx<j>(a[r].x);
            p.y = lx<j>(a[r].y);
            a[r] = cfmav(g.cp, p, cmulv(g.co, a[r]));
        }
    }
}

template <int E, int C, int T>
__device__ __forceinline__ void cnot(float2 (&a)[4], int lane, int wv) {
    constexpr int kc = regPos(E, C), jc = lanePos(E, C), mc = wavePos(E, C);
    constexpr int kt = regPos(E, T), jt = lanePos(E, T);
    static_assert(wavePos(E, T) < 0, "cnot target on wave bit");
    if constexpr (kt >= 0) {
        constexpr int mt = 1 << kt;
        if constexpr (kc >= 0) {
            constexpr int mcb = 1 << kc;
#pragma unroll
            for (int r = 0; r < 4; ++r)
                if ((r & mcb) && !(r & mt)) { float2 t = a[r]; a[r] = a[r | mt]; a[r | mt] = t; }
        } else if constexpr (jc >= 0) {
            const bool p = (lane >> jc) & 1;
#pragma unroll
            for (int r = 0; r < 4; ++r)
                if (!(r & mt)) {
                    const float2 lo = a[r], hi = a[r | mt];
                    a[r].x = p ? hi.x : lo.x;       a[r].y = p ? hi.y : lo.y;
                    a[r | mt].x = p ? lo.x : hi.x;  a[r | mt].y = p ? lo.y : hi.y;
                }
        } else {
            if ((wv >> mc) & 1) {
#pragma unroll
                for (int r = 0; r < 4; ++r)
                    if (!(r & mt)) { float2 t = a[r]; a[r] = a[r | mt]; a[r | mt] = t; }
            }
        }
    } else {  // target on lane bit jt
        if constexpr (kc >= 0) {
            constexpr int mcb = 1 << kc;
#pragma unroll
            for (int r = 0; r < 4; ++r)
                if (r & mcb) { a[r].x = lx<jt>(a[r].x); a[r].y = lx<jt>(a[r].y); }
        } else if constexpr (jc >= 0) {
            const bool p = (lane >> jc) & 1;
#pragma unroll
            for (int r = 0; r < 4; ++r) {
                const float px = lx<jt>(a[r].x), py = lx<jt>(a[r].y);
                a[r].x = p ? px : a[r].x;  a[r].y = p ? py : a[r].y;
            }
        } else {
            if ((wv >> mc) & 1) {
#pragma unroll
                for (int r = 0; r < 4; ++r) { a[r].x = lx<jt>(a[r].x); a[r].y = lx<jt>(a[r].y); }
            }
        }
    }
}

// remap: write mapping PE (linear swizzled slots), barrier, read mapping CE.
// No trailing barrier: caller alternates two LDS buffers (WAR separated by the
// next remap's barrier).
template <int PE, int CE>
__device__ __forceinline__ void remap(float2 (&a)[4], int lane, int wv, float2* st) {
    const int wbase = swzl((wv << 8) | (lane << 2));
#pragma unroll
    for (int r = 0; r < 4; ++r) st[wbase ^ r] = a[r];
    __syncthreads();
    const int rbase = swzl(slotOf(PE, stateOf(CE, wv, lane, 0)));
#pragma unroll
    for (int r = 0; r < 4; ++r) {
        const int d = swzl(slotOf(PE, stateOf(CE, 0, 0, r)));  // compile-time folds
        a[r] = st[rbase ^ d];
    }
}

// ============ measurement masks: ring3 (CNOT(w,w+3)) absorbed, GF(2)-derived ============
constexpr int MASKW[12] = {0x124, 0x092, 0x049, 0x900, 0x480, 0x240,
                           0x920, 0x490, 0x248, 0x924, 0x492, 0x249};
constexpr int rmOf(int w) { int v = 0; for (int k = 0; k < 2; ++k) v |= ((MASKW[w] >> MP[3].rb[k]) & 1) << k; return v; }
constexpr int lmOf(int w) { int v = 0; for (int j = 0; j < 6; ++j) v |= ((MASKW[w] >> MP[3].lb[j]) & 1) << j; return v; }
constexpr int wmOf(int w) { int v = 0; for (int m = 0; m < 4; ++m) v |= ((MASKW[w] >> MP[3].wb[m]) & 1) << m; return v; }
constexpr int RMa[12] = {rmOf(0),rmOf(1),rmOf(2),rmOf(3),rmOf(4),rmOf(5),rmOf(6),rmOf(7),rmOf(8),rmOf(9),rmOf(10),rmOf(11)};
constexpr int LMa[12] = {lmOf(0),lmOf(1),lmOf(2),lmOf(3),lmOf(4),lmOf(5),lmOf(6),lmOf(7),lmOf(8),lmOf(9),lmOf(10),lmOf(11)};
constexpr int WMa[12] = {wmOf(0),wmOf(1),wmOf(2),wmOf(3),wmOf(4),wmOf(5),wmOf(6),wmOf(7),wmOf(8),wmOf(9),wmOf(10),wmOf(11)};

// ================= gate construction helpers =================
__device__ __forceinline__ void buildRot(int g, const float* __restrict__ q_w, float R[8]) {
    const float phi = q_w[3 * g], th = q_w[3 * g + 1], om = q_w[3 * g + 2];
    float sth, cth, sa, ca, sb, cb;
    sincosf(0.5f * th, &sth, &cth);
    sincosf(0.5f * (phi + om), &sa, &ca);
    sincosf(0.5f * (phi - om), &sb, &cb);
    R[0] = cth * ca;  R[1] = -cth * sa;   // U00
    R[2] = -sth * cb; R[3] = -sth * sb;   // U01
    R[4] = sth * cb;  R[5] = -sth * sb;   // U10
    R[6] = cth * ca;  R[7] = cth * sa;    // U11
}
__device__ __forceinline__ void storeGate(G4* dst, const float R[8]) {
    G4 g;
    g.h[0].co.rr = make_float2(R[0], R[0]); g.h[0].co.im = make_float2(-R[1], R[1]);  // u00
    g.h[0].cp.rr = make_float2(R[2], R[2]); g.h[0].cp.im = make_float2(-R[3], R[3]);  // u01
    g.h[1].co.rr = make_float2(R[6], R[6]); g.h[1].co.im = make_float2(-R[7], R[7]);  // u11
    g.h[1].cp.rr = make_float2(R[4], R[4]); g.h[1].cp.im = make_float2(-R[5], R[5]);  // u10
    *dst = g;
}

// ================= kernel =================
__global__ __launch_bounds__(1024, 8) void hybrid_r12(
    const float* __restrict__ x, const float* __restrict__ proj_w,
    const float* __restrict__ proj_b, const float* __restrict__ ln_w,
    const float* __restrict__ ln_b, const float* __restrict__ q_w,
    const float* __restrict__ h1_w, const float* __restrict__ h1_b,
    const float* __restrict__ h2_w, const float* __restrict__ h2_b,
    float* __restrict__ out) {
    __shared__ float2 st[2][4096];  // 64 KB double-buffered remap
    __shared__ G4 rotU[36];
    __shared__ float hbuf[12];
    __shared__ float red[12 * 16];
    __shared__ float z1[256];
    __shared__ float qz[12];

    const int b = blockIdx.x;
    const int tid = threadIdx.x;   // 0..1023
    const int lane = tid & 63;
    const int wv = tid >> 6;       // 0..15

    // ---- 1a. projection on waves 0..11 (wave j -> output j) ----
    if (wv < 12) {
        const float* xr = x + (size_t)b * D_IN;
        const float* wr = proj_w + wv * D_IN;
        float s = 0.f;
#pragma unroll
        for (int k = 0; k < 12; ++k) s += xr[lane + k * 64] * wr[lane + k * 64];
        s = waveRed(s);
        if (lane == 0) hbuf[wv] = tanhf(s + proj_b[wv]);
    }
    // ---- 1b. shared gates 12..35 built concurrently on wave 12 ----
    if (tid >= 768 && tid < 792) {
        const int g = tid - 768 + 12;
        float R[8];
        buildRot(g, q_w, R);
        storeGate(&rotU[g], R);
    }
    __syncthreads();

    // ---- 2. fused L0 gates: one per wave (lane 0 of waves 0..11) ----
    if (lane == 0 && wv < 12) {
        float mu = 0.f;
#pragma unroll
        for (int k = 0; k < 12; ++k) mu += hbuf[k];
        mu *= (1.f / 12.f);
        float var = 0.f;
#pragma unroll
        for (int k = 0; k < 12; ++k) { const float d = hbuf[k] - mu; var += d * d; }
        var *= (1.f / 12.f);
        const float inv = 1.f / sqrtf(var + 1e-5f);
        const float ang = (hbuf[wv] - mu) * inv * ln_w[wv] + ln_b[wv];
        float sy, cy;
        sincosf(0.5f * ang, &sy, &cy);
        float R[8];
        buildRot(wv, q_w, R);
        float M[8];
        M[0] = R[0] * cy + R[2] * sy;  M[1] = R[1] * cy + R[3] * sy;
        M[2] = -R[0] * sy + R[2] * cy; M[3] = -R[1] * sy + R[3] * cy;
        M[4] = R[4] * cy + R[6] * sy;  M[5] = R[5] * cy + R[7] * sy;
        M[6] = -R[4] * sy + R[6] * cy; M[7] = -R[5] * sy + R[7] * cy;
        storeGate(&rotU[wv], M);
    }
    __syncthreads();

    // ---- 3. state |0..0>: E0 maps i=0 -> wv0,lane0,r0 ----
    float2 a[4];
#pragma unroll
    for (int r = 0; r < 4; ++r) a[r] = make_float2(0.f, 0.f);
    if (tid == 0) a[0].x = 1.f;

    // ---- 4. circuit ----
    // E0: reg={10,11} lane={4..9} wave={0,1,2,3}
    rotg<0, 11>(a, lane, rotU + 0); rotg<0, 10>(a, lane, rotU + 1); rotg<0, 9>(a, lane, rotU + 2);
    rotg<0, 8>(a, lane, rotU + 3);  rotg<0, 7>(a, lane, rotU + 4);  rotg<0, 6>(a, lane, rotU + 5);
    rotg<0, 5>(a, lane, rotU + 6);  rotg<0, 4>(a, lane, rotU + 7);
    cnot<0, 11, 10>(a, lane, wv); cnot<0, 10, 9>(a, lane, wv); cnot<0, 9, 8>(a, lane, wv);
    cnot<0, 8, 7>(a, lane, wv);   cnot<0, 7, 6>(a, lane, wv);  cnot<0, 6, 5>(a, lane, wv);
    cnot<0, 5, 4>(a, lane, wv);
    remap<0, 1>(a, lane, wv, st[0]);
    // E1: reg={0,1} lane={2,3,8,9,10,11} wave={4,5,6,7}
    rotg<1, 3>(a, lane, rotU + 8); rotg<1, 2>(a, lane, rotU + 9);
    rotg<1, 1>(a, lane, rotU + 10); rotg<1, 0>(a, lane, rotU + 11);
    cnot<1, 4, 3>(a, lane, wv); cnot<1, 3, 2>(a, lane, wv); cnot<1, 2, 1>(a, lane, wv);
    cnot<1, 1, 0>(a, lane, wv); cnot<1, 0, 11>(a, lane, wv);
    rotg<1, 11>(a, lane, rotU + 12); rotg<1, 10>(a, lane, rotU + 13);
    rotg<1, 9>(a, lane, rotU + 14);  rotg<1, 8>(a, lane, rotU + 15);
    rotg<1, 3>(a, lane, rotU + 20);  rotg<1, 2>(a, lane, rotU + 21);
    rotg<1, 1>(a, lane, rotU + 22);  rotg<1, 0>(a, lane, rotU + 23);
    cnot<1, 11, 9>(a, lane, wv); cnot<1, 10, 8>(a, lane, wv);
    remap<1, 2>(a, lane, wv, st[1]);
    // E2: reg={6,7} lane={5,4,2,3,0,1} wave={8,9,10,11}
    rotg<2, 7>(a, lane, rotU + 16); rotg<2, 6>(a, lane, rotU + 17);
    rotg<2, 5>(a, lane, rotU + 18); rotg<2, 4>(a, lane, rotU + 19);
    cnot<2, 9, 7>(a, lane, wv); cnot<2, 8, 6>(a, lane, wv); cnot<2, 7, 5>(a, lane, wv);
    cnot<2, 6, 4>(a, lane, wv); cnot<2, 5, 3>(a, lane, wv); cnot<2, 4, 2>(a, lane, wv);
    cnot<2, 3, 1>(a, lane, wv); cnot<2, 2, 0>(a, lane, wv);
    rotg<2, 7>(a, lane, rotU + 28); rotg<2, 6>(a, lane, rotU + 29);
    rotg<2, 5>(a, lane, rotU + 30); rotg<2, 4>(a, lane, rotU + 31);
    rotg<2, 3>(a, lane, rotU + 32); rotg<2, 2>(a, lane, rotU + 33);
    remap<2, 3>(a, lane, wv, st[0]);
    // E3: reg={0,1} lane={2,3,8,9,10,11} wave={4,5,6,7}
    cnot<3, 1, 11>(a, lane, wv); cnot<3, 0, 10>(a, lane, wv);
    rotg<3, 11>(a, lane, rotU + 24); rotg<3, 10>(a, lane, rotU + 25);
    rotg<3, 9>(a, lane, rotU + 26);  rotg<3, 8>(a, lane, rotU + 27);
    rotg<3, 1>(a, lane, rotU + 34);  rotg<3, 0>(a, lane, rotU + 35);
    // ring3 absorbed into measurement masks.

    // ---- 5. measurement via Walsh-Hadamard: 4 butterflies replace 12 signed reductions ----
    {
        const float p0 = a[0].x * a[0].x + a[0].y * a[0].y;
        const float p1 = a[1].x * a[1].x + a[1].y * a[1].y;
        const float p2 = a[2].x * a[2].x + a[2].y * a[2].y;
        const float p3 = a[3].x * a[3].x + a[3].y * a[3].y;
        float Wv[4];
        Wv[0] = wht64(p0 + p1 + p2 + p3, lane);
        Wv[1] = wht64(p0 - p1 + p2 - p3, lane);
        Wv[2] = wht64(p0 + p1 - p2 - p3, lane);
        Wv[3] = wht64(p0 - p1 - p2 + p3, lane);
        // lane L of Wv[m] = sum_l (-1)^{popc(L&l)} s_m(l); wire w lives at lane LMa[w]
#pragma unroll
        for (int w = 0; w < 12; ++w) {
            if (lane == LMa[w]) {
                const float v = Wv[RMa[w]];
                red[w * 16 + wv] = (__popc(wv & WMa[w]) & 1) ? -v : v;
            }
        }
    }
    __syncthreads();
    if (tid < 12) {
        float q = 0.f;
#pragma unroll
        for (int m = 0; m < 16; ++m) q += red[tid * 16 + m];
        qz[tid] = q;
    }
    __syncthreads();

    // ---- 6. MLP hidden: relu(q @ h1_w.T + h1_b) ----
    if (tid < 256) {
        float s = h1_b[tid];
#pragma unroll
        for (int k = 0; k < 12; ++k) s += qz[k] * h1_w[tid * 12 + k];
        z1[tid] = fmaxf(s, 0.f);
    }
    __syncthreads();

    // ---- 7. out = z1 @ h2_w.T + h2_b : waves 0..13, 2 outputs each ----
    if (wv < 14) {
#pragma unroll
        for (int jj = 0; jj < 2; ++jj) {
            const int j = wv * 2 + jj;
            const float* wr = h2_w + j * 256;
            float s = 0.f;
#pragma unroll
            for (int k = 0; k < 4; ++k) s += z1[lane + k * 64] * wr[lane + k * 64];
            s = waveRed(s);
            if (lane == 0) out[(size_t)b * NLAB + j] = s + h2_b[j];
        }
    }
}

extern "C" void kernel_launch(void* const* d_in, const int* in_sizes, int n_in,
                              void* d_out, int out_size, void* d_ws, size_t ws_size,
                              hipStream_t stream) {
    const float* x      = (const float*)d_in[0];
    const float* proj_w = (const float*)d_in[1];
    const float* proj_b = (const float*)d_in[2];
    const float* ln_w   = (const float*)d_in[3];
    const float* ln_b   = (const float*)d_in[4];
    const float* q_w    = (const float*)d_in[5];
    const float* h1_w   = (const float*)d_in[6];
    const float* h1_b   = (const float*)d_in[7];
    const float* h2_w   = (const float*)d_in[8];
    const float* h2_b   = (const float*)d_in[9];
    float* out = (float*)d_out;

    const int B = in_sizes[0] / D_IN;  // 512
    hybrid_r12<<<dim3(B), dim3(1024), 0, stream>>>(x, proj_w, proj_b, ln_w, ln_b,
                                                   q_w, h1_w, h1_b, h2_w, h2_b, out);
}

// Round 16
// 29.625 us; speedup vs baseline: 1.3837x; 1.0032x over previous
//
#include <hip/hip_runtime.h>
#include <math.h>

#define D_IN 768
#define NLAB 28

// ================= bit-location maps per epoch =================
struct Map { int rb[2]; int lb[6]; int wb[4]; };
constexpr Map MP[4] = {
    {{10, 11}, {4, 5, 6, 7, 8, 9}, {0, 1, 2, 3}},
    {{0, 1}, {2, 3, 8, 9, 10, 11}, {4, 5, 6, 7}},
    {{6, 7}, {5, 4, 2, 3, 0, 1}, {8, 9, 10, 11}},   // lb permuted: hot bits 5,4 on DPP lanes
    {{0, 1}, {2, 3, 8, 9, 10, 11}, {4, 5, 6, 7}},
};
constexpr int regPos(int e, int b) { for (int k = 0; k < 2; ++k) if (MP[e].rb[k] == b) return k; return -1; }
constexpr int lanePos(int e, int b) { for (int j = 0; j < 6; ++j) if (MP[e].lb[j] == b) return j; return -1; }
constexpr int wavePos(int e, int b) { for (int m = 0; m < 4; ++m) if (MP[e].wb[m] == b) return m; return -1; }

constexpr int stateOf(int e, int wv, int lane, int r) {
    int i = 0;
    for (int k = 0; k < 2; ++k) i |= ((r >> k) & 1) << MP[e].rb[k];
    for (int j = 0; j < 6; ++j) i |= ((lane >> j) & 1) << MP[e].lb[j];
    for (int m = 0; m < 4; ++m) i |= ((wv >> m) & 1) << MP[e].wb[m];
    return i;
}
constexpr int slotOf(int e, int i) {
    int r = 0, ln = 0, wv = 0;
    for (int k = 0; k < 2; ++k) r |= ((i >> MP[e].rb[k]) & 1) << k;
    for (int j = 0; j < 6; ++j) ln |= ((i >> MP[e].lb[j]) & 1) << j;
    for (int m = 0; m < 4; ++m) wv |= ((i >> MP[e].wb[m]) & 1) << m;
    return (wv << 8) | (ln << 2) | r;
}
constexpr int swzl(int s) { return s ^ (((s >> 4) ^ (s >> 8)) & 15); }  // GF(2)-linear

// ============ cross-lane exchange at distance 2^J — pipe-balanced mix ============
// J0/J1/J3: DPP (VALU). J2/J4: ds_swizzle (LDS pipe, 1 op). J5: shfl (LDS pipe).
template <int J>
__device__ __forceinline__ float lx(float v) {
    if constexpr (J == 0 || J == 1 || J == 3) {
        // xor1: quad_perm[1,0,3,2]=0xB1; xor2: quad_perm[2,3,0,1]=0x4E; xor8: row_ror:8=0x128
        constexpr int ctrl = (J == 0) ? 0xB1 : (J == 1) ? 0x4E : 0x128;
        return __int_as_float(__builtin_amdgcn_update_dpp(
            0, __float_as_int(v), ctrl, 0xF, 0xF, true));
    } else if constexpr (J == 2 || J == 4) {
        constexpr int off = (J == 2) ? 0x101F : 0x401F;  // BitMode xor4 / xor16
        return __int_as_float(__builtin_amdgcn_ds_swizzle(__float_as_int(v), off));
    } else {
        return __shfl_xor(v, 32, 64);
    }
}
__device__ __forceinline__ float waveRed(float v) {
    v += lx<0>(v); v += lx<1>(v); v += lx<2>(v);
    v += lx<3>(v); v += lx<4>(v); v += lx<5>(v);
    return v;
}
// full 64-point Walsh-Hadamard: lane L ends with sum_l (-1)^{popc(L&l)} v(l)
__device__ __forceinline__ float wht64(float v, int lane) {
    { const float t = lx<0>(v); v = (lane & 1)  ? (t - v) : (v + t); }
    { const float t = lx<1>(v); v = (lane & 2)  ? (t - v) : (v + t); }
    { const float t = lx<2>(v); v = (lane & 4)  ? (t - v) : (v + t); }
    { const float t = lx<3>(v); v = (lane & 8)  ? (t - v) : (v + t); }
    { const float t = lx<4>(v); v = (lane & 16) ? (t - v) : (v + t); }
    { const float t = lx<5>(v); v = (lane & 32) ? (t - v) : (v + t); }
    return v;
}

// ======= packed-f32 complex helpers: u stored as rr=(ur,ur), im=(-ui,ui) =======
struct CU2 { float2 rr, im; };   // 16 B
struct GP  { CU2 co, cp; };      // 32 B: {own-coef, partner-coef}
struct G4  { GP h[2]; };         // h[0]={u00,u01}, h[1]={u11,u10}

__device__ __forceinline__ float2 cmulv(const CU2 u, const float2 a) {
    float2 t;
    asm("v_pk_mul_f32 %0, %1, %2 op_sel:[0,1] op_sel_hi:[1,0]"
        : "=v"(t) : "v"(u.im), "v"(a));
    asm("v_pk_fma_f32 %0, %1, %2, %3"
        : "=v"(t) : "v"(u.rr), "v"(a), "v"(t));
    return t;
}
__device__ __forceinline__ float2 cfmav(const CU2 u, const float2 a, float2 acc) {
    asm("v_pk_fma_f32 %0, %1, %2, %3 op_sel:[0,1,0] op_sel_hi:[1,0,1]"
        : "=v"(acc) : "v"(u.im), "v"(a), "v"(acc));
    asm("v_pk_fma_f32 %0, %1, %2, %3"
        : "=v"(acc) : "v"(u.rr), "v"(a), "v"(acc));
    return acc;
}

// ================= gates =================
template <int E, int B>
__device__ __forceinline__ void rotg(float2 (&a)[4], int lane, const G4* __restrict__ gp) {
    constexpr int k = regPos(E, B);
    if constexpr (k >= 0) {
        const GP glo = gp->h[0];  // u00, u01
        const GP ghi = gp->h[1];  // u11, u10
        constexpr int m = 1 << k;
#pragma unroll
        for (int r = 0; r < 4; ++r)
            if (!(r & m)) {
                const float2 a0 = a[r], a1 = a[r | m];
                a[r]     = cfmav(glo.cp, a1, cmulv(glo.co, a0));
                a[r | m] = cfmav(ghi.cp, a0, cmulv(ghi.co, a1));
            }
    } else {
        constexpr int j = lanePos(E, B);
        static_assert(j >= 0, "rot on wave bit");
        const int hi = (lane >> j) & 1;
        const GP g = gp->h[hi];   // lane-indexed 32B read: no cndmask chain
#pragma unroll
        for (int r = 0; r < 4; ++r) {
            float2 p;
            p.x = lx<j>(a[r].x);
            p.y = lx<j>(a[r].y);
            a[r] = cfmav(g.cp, p, cmulv(g.co, a[r]));
        }
    }
}

// fused CNOT(ctrl=reg bit CB, tgt=lane bit B) + Rot(B): Rot·X = column swap, so
// for amps with ctrl=1 the (co,cp) roles swap — compile-time per unrolled r, free.
template <int E, int B, int CB>
__device__ __forceinline__ void rotcx(float2 (&a)[4], int lane, const G4* __restrict__ gp) {
    constexpr int j = lanePos(E, B);
    static_assert(j >= 0, "rotcx target must be lane bit");
    constexpr int kc = regPos(E, CB);
    static_assert(kc >= 0, "rotcx ctrl must be reg bit");
    constexpr int mc = 1 << kc;
    const int hi = (lane >> j) & 1;
    const GP g = gp->h[hi];
#pragma unroll
    for (int r = 0; r < 4; ++r) {
        float2 p;
        p.x = lx<j>(a[r].x);
        p.y = lx<j>(a[r].y);
        if (r & mc)
            a[r] = cfmav(g.co, p, cmulv(g.cp, a[r]));   // ctrl=1: swapped (Rot·X)
        else
            a[r] = cfmav(g.cp, p, cmulv(g.co, a[r]));   // ctrl=0: plain Rot
    }
}

template <int E, int C, int T>
__device__ __forceinline__ void cnot(float2 (&a)[4], int lane, int wv) {
    constexpr int kc = regPos(E, C), jc = lanePos(E, C), mc = wavePos(E, C);
    constexpr int kt = regPos(E, T), jt = lanePos(E, T);
    static_assert(wavePos(E, T) < 0, "cnot target on wave bit");
    if constexpr (kt >= 0) {
        constexpr int mt = 1 << kt;
        if constexpr (kc >= 0) {
            constexpr int mcb = 1 << kc;
#pragma unroll
            for (int r = 0; r < 4; ++r)
                if ((r & mcb) && !(r & mt)) { float2 t = a[r]; a[r] = a[r | mt]; a[r | mt] = t; }
        } else if constexpr (jc >= 0) {
            const bool p = (lane >> jc) & 1;
#pragma unroll
            for (int r = 0; r < 4; ++r)
                if (!(r & mt)) {
                    const float2 lo = a[r], hi = a[r | mt];
                    a[r].x = p ? hi.x : lo.x;       a[r].y = p ? hi.y : lo.y;
                    a[r | mt].x = p ? lo.x : hi.x;  a[r | mt].y = p ? lo.y : hi.y;
                }
        } else {
            if ((wv >> mc) & 1) {
#pragma unroll
                for (int r = 0; r < 4; ++r)
                    if (!(r & mt)) { float2 t = a[r]; a[r] = a[r | mt]; a[r | mt] = t; }
            }
        }
    } else {  // target on lane bit jt
        if constexpr (kc >= 0) {
            constexpr int mcb = 1 << kc;
#pragma unroll
            for (int r = 0; r < 4; ++r)
                if (r & mcb) { a[r].x = lx<jt>(a[r].x); a[r].y = lx<jt>(a[r].y); }
        } else if constexpr (jc >= 0) {
            const bool p = (lane >> jc) & 1;
#pragma unroll
            for (int r = 0; r < 4; ++r) {
                const float px = lx<jt>(a[r].x), py = lx<jt>(a[r].y);
                a[r].x = p ? px : a[r].x;  a[r].y = p ? py : a[r].y;
            }
        } else {
            if ((wv >> mc) & 1) {
#pragma unroll
                for (int r = 0; r < 4; ++r) { a[r].x = lx<jt>(a[r].x); a[r].y = lx<jt>(a[r].y); }
            }
        }
    }
}

// remap: write mapping PE (linear swizzled slots), barrier, read mapping CE.
// No trailing barrier: caller alternates two LDS buffers (WAR separated by the
// next remap's barrier).
template <int PE, int CE>
__device__ __forceinline__ void remap(float2 (&a)[4], int lane, int wv, float2* st) {
    const int wbase = swzl((wv << 8) | (lane << 2));
#pragma unroll
    for (int r = 0; r < 4; ++r) st[wbase ^ r] = a[r];
    __syncthreads();
    const int rbase = swzl(slotOf(PE, stateOf(CE, wv, lane, 0)));
#pragma unroll
    for (int r = 0; r < 4; ++r) {
        const int d = swzl(slotOf(PE, stateOf(CE, 0, 0, r)));  // compile-time folds
        a[r] = st[rbase ^ d];
    }
}

// ============ measurement masks: ring3 (CNOT(w,w+3)) absorbed, GF(2)-derived ============
constexpr int MASKW[12] = {0x124, 0x092, 0x049, 0x900, 0x480, 0x240,
                           0x920, 0x490, 0x248, 0x924, 0x492, 0x249};
constexpr int rmOf(int w) { int v = 0; for (int k = 0; k < 2; ++k) v |= ((MASKW[w] >> MP[3].rb[k]) & 1) << k; return v; }
constexpr int lmOf(int w) { int v = 0; for (int j = 0; j < 6; ++j) v |= ((MASKW[w] >> MP[3].lb[j]) & 1) << j; return v; }
constexpr int wmOf(int w) { int v = 0; for (int m = 0; m < 4; ++m) v |= ((MASKW[w] >> MP[3].wb[m]) & 1) << m; return v; }
constexpr int RMa[12] = {rmOf(0),rmOf(1),rmOf(2),rmOf(3),rmOf(4),rmOf(5),rmOf(6),rmOf(7),rmOf(8),rmOf(9),rmOf(10),rmOf(11)};
constexpr int LMa[12] = {lmOf(0),lmOf(1),lmOf(2),lmOf(3),lmOf(4),lmOf(5),lmOf(6),lmOf(7),lmOf(8),lmOf(9),lmOf(10),lmOf(11)};
constexpr int WMa[12] = {wmOf(0),wmOf(1),wmOf(2),wmOf(3),wmOf(4),wmOf(5),wmOf(6),wmOf(7),wmOf(8),wmOf(9),wmOf(10),wmOf(11)};

// ================= gate construction helpers =================
__device__ __forceinline__ void buildRot(int g, const float* __restrict__ q_w, float R[8]) {
    const float phi = q_w[3 * g], th = q_w[3 * g + 1], om = q_w[3 * g + 2];
    float sth, cth, sa, ca, sb, cb;
    sincosf(0.5f * th, &sth, &cth);
    sincosf(0.5f * (phi + om), &sa, &ca);
    sincosf(0.5f * (phi - om), &sb, &cb);
    R[0] = cth * ca;  R[1] = -cth * sa;   // U00
    R[2] = -sth * cb; R[3] = -sth * sb;   // U01
    R[4] = sth * cb;  R[5] = -sth * sb;   // U10
    R[6] = cth * ca;  R[7] = cth * sa;    // U11
}
__device__ __forceinline__ void storeGate(G4* dst, const float R[8]) {
    G4 g;
    g.h[0].co.rr = make_float2(R[0], R[0]); g.h[0].co.im = make_float2(-R[1], R[1]);  // u00
    g.h[0].cp.rr = make_float2(R[2], R[2]); g.h[0].cp.im = make_float2(-R[3], R[3]);  // u01
    g.h[1].co.rr = make_float2(R[6], R[6]); g.h[1].co.im = make_float2(-R[7], R[7]);  // u11
    g.h[1].cp.rr = make_float2(R[4], R[4]); g.h[1].cp.im = make_float2(-R[5], R[5]);  // u10
    *dst = g;
}

// ================= kernel =================
__global__ __launch_bounds__(1024, 8) void hybrid_r16(
    const float* __restrict__ x, const float* __restrict__ proj_w,
    const float* __restrict__ proj_b, const float* __restrict__ ln_w,
    const float* __restrict__ ln_b, const float* __restrict__ q_w,
    const float* __restrict__ h1_w, const float* __restrict__ h1_b,
    const float* __restrict__ h2_w, const float* __restrict__ h2_b,
    float* __restrict__ out) {
    __shared__ float2 st[2][4096];  // 64 KB double-buffered remap
    __shared__ G4 rotU[36];
    __shared__ float hbuf[12];
    __shared__ float red[12 * 16];
    __shared__ float z1[256];
    __shared__ float qz[12];

    const int b = blockIdx.x;
    const int tid = threadIdx.x;   // 0..1023
    const int lane = tid & 63;
    const int wv = tid >> 6;       // 0..15

    // ---- 1a. projection on waves 0..11 (wave j -> output j) ----
    if (wv < 12) {
        const float* xr = x + (size_t)b * D_IN;
        const float* wr = proj_w + wv * D_IN;
        float s = 0.f;
#pragma unroll
        for (int k = 0; k < 12; ++k) s += xr[lane + k * 64] * wr[lane + k * 64];
        s = waveRed(s);
        if (lane == 0) hbuf[wv] = tanhf(s + proj_b[wv]);
    }
    // ---- 1b. shared gates 12..35 built concurrently on wave 12 ----
    if (tid >= 768 && tid < 792) {
        const int g = tid - 768 + 12;
        float R[8];
        buildRot(g, q_w, R);
        storeGate(&rotU[g], R);
    }
    __syncthreads();

    // ---- 2. fused L0 gates: one per wave (lane 0 of waves 0..11) ----
    if (lane == 0 && wv < 12) {
        float mu = 0.f;
#pragma unroll
        for (int k = 0; k < 12; ++k) mu += hbuf[k];
        mu *= (1.f / 12.f);
        float var = 0.f;
#pragma unroll
        for (int k = 0; k < 12; ++k) { const float d = hbuf[k] - mu; var += d * d; }
        var *= (1.f / 12.f);
        const float inv = 1.f / sqrtf(var + 1e-5f);
        const float ang = (hbuf[wv] - mu) * inv * ln_w[wv] + ln_b[wv];
        float sy, cy;
        sincosf(0.5f * ang, &sy, &cy);
        float R[8];
        buildRot(wv, q_w, R);
        float M[8];
        M[0] = R[0] * cy + R[2] * sy;  M[1] = R[1] * cy + R[3] * sy;
        M[2] = -R[0] * sy + R[2] * cy; M[3] = -R[1] * sy + R[3] * cy;
        M[4] = R[4] * cy + R[6] * sy;  M[5] = R[5] * cy + R[7] * sy;
        M[6] = -R[4] * sy + R[6] * cy; M[7] = -R[5] * sy + R[7] * cy;
        storeGate(&rotU[wv], M);
    }
    __syncthreads();

    // ---- 3. state |0..0>: E0 maps i=0 -> wv0,lane0,r0 ----
    float2 a[4];
#pragma unroll
    for (int r = 0; r < 4; ++r) a[r] = make_float2(0.f, 0.f);
    if (tid == 0) a[0].x = 1.f;

    // ---- 4. circuit ----
    // E0: reg={10,11} lane={4..9} wave={0,1,2,3}
    rotg<0, 11>(a, lane, rotU + 0); rotg<0, 10>(a, lane, rotU + 1); rotg<0, 9>(a, lane, rotU + 2);
    rotg<0, 8>(a, lane, rotU + 3);  rotg<0, 7>(a, lane, rotU + 4);  rotg<0, 6>(a, lane, rotU + 5);
    rotg<0, 5>(a, lane, rotU + 6);  rotg<0, 4>(a, lane, rotU + 7);
    cnot<0, 11, 10>(a, lane, wv); cnot<0, 10, 9>(a, lane, wv); cnot<0, 9, 8>(a, lane, wv);
    cnot<0, 8, 7>(a, lane, wv);   cnot<0, 7, 6>(a, lane, wv);  cnot<0, 6, 5>(a, lane, wv);
    cnot<0, 5, 4>(a, lane, wv);
    remap<0, 1>(a, lane, wv, st[0]);
    // E1: reg={0,1} lane={2,3,8,9,10,11} wave={4,5,6,7}
    rotg<1, 3>(a, lane, rotU + 8); rotg<1, 2>(a, lane, rotU + 9);
    rotg<1, 1>(a, lane, rotU + 10); rotg<1, 0>(a, lane, rotU + 11);
    cnot<1, 4, 3>(a, lane, wv); cnot<1, 3, 2>(a, lane, wv); cnot<1, 2, 1>(a, lane, wv);
    cnot<1, 1, 0>(a, lane, wv);
    rotcx<1, 11, 0>(a, lane, rotU + 12);   // fused CNOT(0,11)+Rot(11)
    rotg<1, 10>(a, lane, rotU + 13);
    rotg<1, 9>(a, lane, rotU + 14);  rotg<1, 8>(a, lane, rotU + 15);
    rotg<1, 3>(a, lane, rotU + 20);  rotg<1, 2>(a, lane, rotU + 21);
    rotg<1, 1>(a, lane, rotU + 22);  rotg<1, 0>(a, lane, rotU + 23);
    cnot<1, 11, 9>(a, lane, wv); cnot<1, 10, 8>(a, lane, wv);
    remap<1, 2>(a, lane, wv, st[1]);
    // E2: reg={6,7} lane={5,4,2,3,0,1} wave={8,9,10,11}
    rotg<2, 7>(a, lane, rotU + 16); rotg<2, 6>(a, lane, rotU + 17);
    rotg<2, 5>(a, lane, rotU + 18); rotg<2, 4>(a, lane, rotU + 19);
    cnot<2, 9, 7>(a, lane, wv); cnot<2, 8, 6>(a, lane, wv); cnot<2, 7, 5>(a, lane, wv);
    cnot<2, 6, 4>(a, lane, wv); cnot<2, 5, 3>(a, lane, wv); cnot<2, 4, 2>(a, lane, wv);
    cnot<2, 3, 1>(a, lane, wv); cnot<2, 2, 0>(a, lane, wv);
    rotg<2, 7>(a, lane, rotU + 28); rotg<2, 6>(a, lane, rotU + 29);
    rotg<2, 5>(a, lane, rotU + 30); rotg<2, 4>(a, lane, rotU + 31);
    rotg<2, 3>(a, lane, rotU + 32); rotg<2, 2>(a, lane, rotU + 33);
    remap<2, 3>(a, lane, wv, st[0]);
    // E3: reg={0,1} lane={2,3,8,9,10,11} wave={4,5,6,7}
    rotcx<3, 11, 1>(a, lane, rotU + 24);   // fused CNOT(1,11)+Rot(11)
    rotcx<3, 10, 0>(a, lane, rotU + 25);   // fused CNOT(0,10)+Rot(10) [commutes past (1,11)]
    rotg<3, 9>(a, lane, rotU + 26);  rotg<3, 8>(a, lane, rotU + 27);
    rotg<3, 1>(a, lane, rotU + 34);  rotg<3, 0>(a, lane, rotU + 35);
    // ring3 absorbed into measurement masks.

    // ---- 5. measurement via Walsh-Hadamard: 4 butterflies replace 12 signed reductions ----
    {
        const float p0 = a[0].x * a[0].x + a[0].y * a[0].y;
        const float p1 = a[1].x * a[1].x + a[1].y * a[1].y;
        const float p2 = a[2].x * a[2].x + a[2].y * a[2].y;
        const float p3 = a[3].x * a[3].x + a[3].y * a[3].y;
        float Wv[4];
        Wv[0] = wht64(p0 + p1 + p2 + p3, lane);
        Wv[1] = wht64(p0 - p1 + p2 - p3, lane);
        Wv[2] = wht64(p0 + p1 - p2 - p3, lane);
        Wv[3] = wht64(p0 - p1 - p2 + p3, lane);
        // lane L of Wv[m] = sum_l (-1)^{popc(L&l)} s_m(l); wire w lives at lane LMa[w]
#pragma unroll
        for (int w = 0; w < 12; ++w) {
            if (lane == LMa[w]) {
                const float v = Wv[RMa[w]];
                red[w * 16 + wv] = (__popc(wv & WMa[w]) & 1) ? -v : v;
            }
        }
    }
    __syncthreads();
    if (tid < 12) {
        float q = 0.f;
#pragma unroll
        for (int m = 0; m < 16; ++m) q += red[tid * 16 + m];
        qz[tid] = q;
    }
    __syncthreads();

    // ---- 6. MLP hidden: relu(q @ h1_w.T + h1_b) ----
    if (tid < 256) {
        float s = h1_b[tid];
#pragma unroll
        for (int k = 0; k < 12; ++k) s += qz[k] * h1_w[tid * 12 + k];
        z1[tid] = fmaxf(s, 0.f);
    }
    __syncthreads();

    // ---- 7. out = z1 @ h2_w.T + h2_b : waves 0..13, 2 outputs each ----
    if (wv < 14) {
#pragma unroll
        for (int jj = 0; jj < 2; ++jj) {
            const int j = wv * 2 + jj;
            const float* wr = h2_w + j * 256;
            float s = 0.f;
#pragma unroll
            for (int k = 0; k < 4; ++k) s += z1[lane + k * 64] * wr[lane + k * 64];
            s = waveRed(s);
            if (lane == 0) out[(size_t)b * NLAB + j] = s + h2_b[j];
        }
    }
}

extern "C" void kernel_launch(void* const* d_in, const int* in_sizes, int n_in,
                              void* d_out, int out_size, void* d_ws, size_t ws_size,
                              hipStream_t stream) {
    const float* x      = (const float*)d_in[0];
    const float* proj_w = (const float*)d_in[1];
    const float* proj_b = (const float*)d_in[2];
    const float* ln_w   = (const float*)d_in[3];
    const float* ln_b   = (const float*)d_in[4];
    const float* q_w    = (const float*)d_in[5];
    const float* h1_w   = (const float*)d_in[6];
    const float* h1_b   = (const float*)d_in[7];
    const float* h2_w   = (const float*)d_in[8];
    const float* h2_b   = (const float*)d_in[9];
    float* out = (float*)d_out;

    const int B = in_sizes[0] / D_IN;  // 512
    hybrid_r16<<<dim3(B), dim3(1024), 0, stream>>>(x, proj_w, proj_b, ln_w, ln_b,
                                                   q_w, h1_w, h1_b, h2_w, h2_b, out);
}